// Round 8
// baseline (1926.484 us; speedup 1.0000x reference)
//
#include <hip/hip_runtime.h>

// LiquidNN LTC: B=512, S=512, D=H=128, O=1, UNFOLDS=6, dt=0.1, tau=1.
// ROUND 8: R7 MFMA structure + stall surgery.
//
// R7 post-mortem: 1334 cyc/phase, but visible work only ~200 cyc -> stalls.
// (a) __syncthreads lowers to s_waitcnt vmcnt(0) lgkmcnt(0); s_barrier.
//     The per-step x prefetch (HBM, ~900 cyc) is drained at the FIRST
//     barrier after issue -- every step, all rounds. Fix: raw s_barrier
//     with manual lgkmcnt(0) (write->wait->barrier->read is sound; the
//     x-load's vmcnt is waited only at its use at u==3).
// (b) 4-deep serial MFMA K-chains (~160 cyc exposed). Fix: two 2-deep
//     chains per tile + f32x4 add; 8 independent chains across 2 tiles.
//
// Structure (unchanged from R7, which PASSED): G=16 batch rows/block,
// 32 blocks x 4 waves. W_r[128x128] @ H[128x16] via mfma_f32_16x16x32_f16;
// wave owns 2 M-tiles; C preloaded with xin+b_in+b_r; h fp32 in registers.

typedef _Float16 v8hf __attribute__((ext_vector_type(8)));
typedef _Float16 v4hf __attribute__((ext_vector_type(4)));
typedef float    f32x4 __attribute__((ext_vector_type(4)));

#define S_LEN 512
#define HDIM  128
#define NUNF  6
#define DTC   0.1f
#define GRP   16

__device__ __forceinline__ float fast_tanh(float y) {
    // tanh(y) = 1 - 2/(e^{2y}+1); v_exp/v_rcp based, NaN-free at +-inf
    float u = __expf(2.0f * y);
    return 1.0f - __fdividef(2.0f, u + 1.0f);
}

// A-fragment: 8 consecutive f32 at W[row][kofs..kofs+8) -> v8hf.
__device__ __forceinline__ v8hf ld_afrag(const float* W, int row, int kofs) {
    const float4* p = reinterpret_cast<const float4*>(W + (size_t)row * HDIM + kofs);
    float4 a = p[0], b = p[1];
    return v8hf{(_Float16)a.x, (_Float16)a.y, (_Float16)a.z, (_Float16)a.w,
                (_Float16)b.x, (_Float16)b.y, (_Float16)b.z, (_Float16)b.w};
}

#define MFMA(A, B, C) __builtin_amdgcn_mfma_f32_16x16x32_f16(A, B, C, 0, 0, 0)
#define PIN(V) asm volatile("" : "+v"(V))

// Raw barrier: LDS writes made visible (lgkmcnt(0)) then s_barrier.
// Does NOT drain vmcnt -> the per-step HBM x-prefetch stays in flight
// (the __syncthreads vmcnt(0) drain was R7's main stall).
#define BAR() do {                                        \
    __builtin_amdgcn_sched_barrier(0);                    \
    asm volatile("s_waitcnt lgkmcnt(0)" ::: "memory");    \
    __builtin_amdgcn_s_barrier();                         \
    __builtin_amdgcn_sched_barrier(0);                    \
} while (0)

// Read the 4 K-tile B-fragments (frag-ordered LDS: v8hf index kt*64+lane).
#define RDFRAGS(BUFP, F0, F1, F2, F3) do {                                  \
    const v8hf* _q = reinterpret_cast<const v8hf*>(BUFP);                   \
    F0 = _q[lane]; F1 = _q[64 + lane]; F2 = _q[128 + lane]; F3 = _q[192 + lane]; \
} while (0)

// tanh + ODE update (authoritative fp32 h) + packed f16 write-back.
#define UPDATE_TILE(HACC, ACC, WO, WB) do {                                 \
    float v0_ = fast_tanh(ACC[0]);                                          \
    float v1_ = fast_tanh(ACC[1]);                                          \
    float v2_ = fast_tanh(ACC[2]);                                          \
    float v3_ = fast_tanh(ACC[3]);                                          \
    HACC[0] += DTC * (v0_ - HACC[0]);                                       \
    HACC[1] += DTC * (v1_ - HACC[1]);                                       \
    HACC[2] += DTC * (v2_ - HACC[2]);                                       \
    HACC[3] += DTC * (v3_ - HACC[3]);                                       \
    *reinterpret_cast<v4hf*>(&Hf[WB][WO]) =                                 \
        v4hf{(_Float16)HACC[0], (_Float16)HACC[1],                          \
             (_Float16)HACC[2], (_Float16)HACC[3]};                         \
} while (0)

__global__ __launch_bounds__(256)
__attribute__((amdgpu_waves_per_eu(1, 1)))
void ltc_kernel(const float* __restrict__ x,
                const float* __restrict__ W_in,
                const float* __restrict__ b_in,
                const float* __restrict__ W_r,
                const float* __restrict__ b_r,
                const float* __restrict__ W_fc,
                const float* __restrict__ b_fc,
                float* __restrict__ out)
{
    const int tid  = threadIdx.x;    // 0..255 (4 waves)
    const int wave = tid >> 6;
    const int lane = tid & 63;
    const int nn   = lane & 15;      // A-row / B-col / D-col
    const int lg   = lane >> 4;      // lane group 0..3
    const int b0   = blockIdx.x * GRP;

    // H/X in B-fragment order: f16 index = kt*512 + lane*8 + i, holding
    // element (k = kt*32 + 8*(lane>>4) + i, n = lane&15).
    __shared__ __align__(16) _Float16 Hf[2][2048];
    __shared__ __align__(16) _Float16 Xf[2][2048];
    __shared__ float red[4][GRP];

    const int mb0 = wave * 32;       // M-tile 0 row base
    const int mb1 = wave * 32 + 16;  // M-tile 1 row base

    // ---- A-fragments: 8 v8hf per matrix per wave (64 VGPR total) ----
    v8hf wr00 = ld_afrag(W_r,  mb0 + nn,  0 + lg * 8);
    v8hf wr01 = ld_afrag(W_r,  mb0 + nn, 32 + lg * 8);
    v8hf wr02 = ld_afrag(W_r,  mb0 + nn, 64 + lg * 8);
    v8hf wr03 = ld_afrag(W_r,  mb0 + nn, 96 + lg * 8);
    v8hf wr10 = ld_afrag(W_r,  mb1 + nn,  0 + lg * 8);
    v8hf wr11 = ld_afrag(W_r,  mb1 + nn, 32 + lg * 8);
    v8hf wr12 = ld_afrag(W_r,  mb1 + nn, 64 + lg * 8);
    v8hf wr13 = ld_afrag(W_r,  mb1 + nn, 96 + lg * 8);
    v8hf wi00 = ld_afrag(W_in, mb0 + nn,  0 + lg * 8);
    v8hf wi01 = ld_afrag(W_in, mb0 + nn, 32 + lg * 8);
    v8hf wi02 = ld_afrag(W_in, mb0 + nn, 64 + lg * 8);
    v8hf wi03 = ld_afrag(W_in, mb0 + nn, 96 + lg * 8);
    v8hf wi10 = ld_afrag(W_in, mb1 + nn,  0 + lg * 8);
    v8hf wi11 = ld_afrag(W_in, mb1 + nn, 32 + lg * 8);
    v8hf wi12 = ld_afrag(W_in, mb1 + nn, 64 + lg * 8);
    v8hf wi13 = ld_afrag(W_in, mb1 + nn, 96 + lg * 8);

    // ---- per-lane D rows, biases, H write offsets ----
    const int row0 = mb0 + 4 * lg;   // D rows row0..row0+3 (tile 0)
    const int row1 = mb1 + 4 * lg;
    f32x4 bias0, bias1;
#pragma unroll
    for (int r = 0; r < 4; ++r) {
        bias0[r] = b_in[row0 + r] + b_r[row0 + r];
        bias1[r] = b_in[row1 + r] + b_r[row1 + r];
    }
    // frag-store f16 index for (m=row, n): (m>>5)*512+(((m&31)>>3)*16+n)*8+(m&7)
    const int w0 = (row0 >> 5) * 512 + (((row0 & 31) >> 3) * 16 + nn) * 8 + (row0 & 7);
    const int w1 = (row1 >> 5) * 512 + (((row1 & 31) >> 3) * 16 + nn) * 8 + (row1 & 7);

    // ---- X staging map: thread loads 8 f32 of x[b0+xg][s][xseg*8..] ----
    const int xg = tid >> 4, xseg = tid & 15;
    const float* xbase = x + ((size_t)(b0 + xg) * S_LEN) * HDIM + xseg * 8;
    const int xw = (xseg >> 2) * 512 + ((xseg & 3) * 16 + xg) * 8;

    // ---- prologue: zero H state, stage X[0] ----
    {
        const float4* xp = reinterpret_cast<const float4*>(xbase);
        float4 a = xp[0], b = xp[1];
        *reinterpret_cast<v8hf*>(&Xf[0][xw]) =
            v8hf{(_Float16)a.x, (_Float16)a.y, (_Float16)a.z, (_Float16)a.w,
                 (_Float16)b.x, (_Float16)b.y, (_Float16)b.z, (_Float16)b.w};
        const _Float16 z = (_Float16)0.0f;
        *reinterpret_cast<v8hf*>(&Hf[0][tid * 8]) = v8hf{z, z, z, z, z, z, z, z};
    }
    __syncthreads();

    f32x4 h0 = {0.f, 0.f, 0.f, 0.f};   // authoritative fp32 h, tile 0 rows
    f32x4 h1 = {0.f, 0.f, 0.f, 0.f};
    const f32x4 z4 = {0.f, 0.f, 0.f, 0.f};

#pragma unroll 1
    for (int s = 0; s < S_LEN; ++s) {
        // in-loop pins: keep all 16 weight frags loop-carried in VGPRs
        PIN(wr00); PIN(wr01); PIN(wr02); PIN(wr03);
        PIN(wr10); PIN(wr11); PIN(wr12); PIN(wr13);
        PIN(wi00); PIN(wi01); PIN(wi02); PIN(wi03);
        PIN(wi10); PIN(wi11); PIN(wi12); PIN(wi13);

        // prefetch next step's x into regs (HBM latency spans the whole step
        // now that barriers no longer drain vmcnt; waited only at u==3 use)
        float4 pa = {0.f, 0.f, 0.f, 0.f}, pb = {0.f, 0.f, 0.f, 0.f};
        if (s + 1 < S_LEN) {
            const float4* xp =
                reinterpret_cast<const float4*>(xbase + (size_t)(s + 1) * HDIM);
            pa = xp[0]; pb = xp[1];
        }

        // ---- phase 0: input map (X MFMA) fused with unfold 0 ----
        f32x4 xin0, xin1;
        {
            v8hf X0, X1, X2, X3, B0, B1, B2, B3;
            RDFRAGS(&Xf[s & 1][0], X0, X1, X2, X3);
            RDFRAGS(&Hf[0][0],     B0, B1, B2, B3);
            // two 2-deep chains per accumulation (8 independent chains total)
            f32x4 xa0 = MFMA(wi01, X1, MFMA(wi00, X0, bias0));
            f32x4 xb0 = MFMA(wi03, X3, MFMA(wi02, X2, z4));
            f32x4 xa1 = MFMA(wi11, X1, MFMA(wi10, X0, bias1));
            f32x4 xb1 = MFMA(wi13, X3, MFMA(wi12, X2, z4));
            f32x4 ha0 = MFMA(wr01, B1, MFMA(wr00, B0, z4));
            f32x4 hb0 = MFMA(wr03, B3, MFMA(wr02, B2, z4));
            f32x4 ha1 = MFMA(wr11, B1, MFMA(wr10, B0, z4));
            f32x4 hb1 = MFMA(wr13, B3, MFMA(wr12, B2, z4));
            xin0 = xa0 + xb0;
            xin1 = xa1 + xb1;
            f32x4 t0 = xin0 + (ha0 + hb0);
            f32x4 t1 = xin1 + (ha1 + hb1);
            UPDATE_TILE(h0, t0, w0, 1);
            UPDATE_TILE(h1, t1, w1, 1);
        }
        BAR();

        // ---- unfolds 1..5 ----
#pragma unroll
        for (int u = 1; u < NUNF; ++u) {
            v8hf B0, B1, B2, B3;
            RDFRAGS(&Hf[u & 1][0], B0, B1, B2, B3);
            f32x4 pa0 = MFMA(wr01, B1, MFMA(wr00, B0, xin0));  // C carries xin+biases
            f32x4 pb0 = MFMA(wr03, B3, MFMA(wr02, B2, z4));
            f32x4 pa1 = MFMA(wr11, B1, MFMA(wr10, B0, xin1));
            f32x4 pb1 = MFMA(wr13, B3, MFMA(wr12, B2, z4));
            f32x4 t0 = pa0 + pb0;
            f32x4 t1 = pa1 + pb1;
            UPDATE_TILE(h0, t0, w0, (u + 1) & 1);
            UPDATE_TILE(h1, t1, w1, (u + 1) & 1);
            if (u == 3 && s + 1 < S_LEN) {   // vmcnt waited HERE, not at barriers
                *reinterpret_cast<v8hf*>(&Xf[(s + 1) & 1][xw]) =
                    v8hf{(_Float16)pa.x, (_Float16)pa.y, (_Float16)pa.z, (_Float16)pa.w,
                         (_Float16)pb.x, (_Float16)pb.y, (_Float16)pb.z, (_Float16)pb.w};
            }
            BAR();
        }
    }

    // ---- epilogue: out[b0+n] = sum_m h[m][n]*W_fc[m] + b_fc ----
    float p = 0.f;
#pragma unroll
    for (int r = 0; r < 4; ++r) p += h0[r] * W_fc[row0 + r];
#pragma unroll
    for (int r = 0; r < 4; ++r) p += h1[r] * W_fc[row1 + r];
    p += __shfl_xor(p, 16);
    p += __shfl_xor(p, 32);
    if (lane < 16) red[wave][lane] = p;
    __syncthreads();
    if (tid < GRP)
        out[b0 + tid] = red[0][tid] + red[1][tid] + red[2][tid] + red[3][tid] + b_fc[0];
}

extern "C" void kernel_launch(void* const* d_in, const int* in_sizes, int n_in,
                              void* d_out, int out_size, void* d_ws, size_t ws_size,
                              hipStream_t stream) {
    const float* x    = (const float*)d_in[0];
    const float* W_in = (const float*)d_in[1];
    const float* b_in = (const float*)d_in[2];
    const float* W_r  = (const float*)d_in[3];
    const float* b_r  = (const float*)d_in[4];
    const float* W_fc = (const float*)d_in[5];
    const float* b_fc = (const float*)d_in[6];
    float* outp = (float*)d_out;
    (void)in_sizes; (void)n_in; (void)out_size; (void)d_ws; (void)ws_size;
    ltc_kernel<<<dim3(512 / GRP), dim3(256), 0, stream>>>(x, W_in, b_in, W_r, b_r, W_fc, b_fc, outp);
}

// Round 9
// 1600.818 us; speedup vs baseline: 1.2034x; 1.2034x over previous
//
#include <hip/hip_runtime.h>

// LiquidNN LTC: B=512, S=512, D=H=128, O=1, UNFOLDS=6, dt=0.1, tau=1.
// ROUND 9: 8-wave lean MFMA. Wall time = 3072 phases x single-chain latency;
// R8's chain = ~740 cyc per-wave issue (8 tanh/lane = 16 quarter-rate trans
// ops = 256 cyc + zero-init movs + merge adds) + ~150 MFMA + ~500 LDS/barrier.
// Fix: (a) 8 waves x 1 M-tile -> 4 tanh/lane (trans 128), 4 MFMA/wave,
// 32 VGPR of weights (allocator-proven scale); (b) single 4-deep MFMA chain
// with C preloaded = xin (no z4 zero-movs, no merge adds); (c) same verified
// fragment layouts / staging / BAR() as the PASSED R8 kernel.

typedef _Float16 v8hf __attribute__((ext_vector_type(8)));
typedef _Float16 v4hf __attribute__((ext_vector_type(4)));
typedef float    f32x4 __attribute__((ext_vector_type(4)));

#define S_LEN 512
#define HDIM  128
#define NUNF  6
#define DTC   0.1f
#define GRP   16

__device__ __forceinline__ float fast_tanh(float y) {
    // tanh(y) = 1 - 2/(e^{2y}+1); v_exp/v_rcp based, NaN-free at +-inf
    float u = __expf(2.0f * y);
    return 1.0f - __fdividef(2.0f, u + 1.0f);
}

// A-fragment: 8 consecutive f32 at W[row][kofs..kofs+8) -> v8hf.
__device__ __forceinline__ v8hf ld_afrag(const float* W, int row, int kofs) {
    const float4* p = reinterpret_cast<const float4*>(W + (size_t)row * HDIM + kofs);
    float4 a = p[0], b = p[1];
    return v8hf{(_Float16)a.x, (_Float16)a.y, (_Float16)a.z, (_Float16)a.w,
                (_Float16)b.x, (_Float16)b.y, (_Float16)b.z, (_Float16)b.w};
}

#define MFMA(A, B, C) __builtin_amdgcn_mfma_f32_16x16x32_f16(A, B, C, 0, 0, 0)
#define PIN(V) asm volatile("" : "+v"(V))

// Raw barrier (R8-proven): LDS writes visible (lgkmcnt(0)) then s_barrier.
// Does not drain vmcnt -> x prefetch stays in flight across phases.
#define BAR() do {                                        \
    __builtin_amdgcn_sched_barrier(0);                    \
    asm volatile("s_waitcnt lgkmcnt(0)" ::: "memory");    \
    __builtin_amdgcn_s_barrier();                         \
    __builtin_amdgcn_sched_barrier(0);                    \
} while (0)

// Read the 4 K-tile B-fragments (frag-ordered LDS: v8hf index kt*64+lane).
#define RDFRAGS(BUFP, F0, F1, F2, F3) do {                                  \
    const v8hf* _q = reinterpret_cast<const v8hf*>(BUFP);                   \
    F0 = _q[lane]; F1 = _q[64 + lane]; F2 = _q[128 + lane]; F3 = _q[192 + lane]; \
} while (0)

__global__ __launch_bounds__(512)
__attribute__((amdgpu_waves_per_eu(2, 2)))
void ltc_kernel(const float* __restrict__ x,
                const float* __restrict__ W_in,
                const float* __restrict__ b_in,
                const float* __restrict__ W_r,
                const float* __restrict__ b_r,
                const float* __restrict__ W_fc,
                const float* __restrict__ b_fc,
                float* __restrict__ out)
{
    const int tid  = threadIdx.x;    // 0..511 (8 waves)
    const int wave = tid >> 6;       // 0..7 -> M-tile
    const int lane = tid & 63;
    const int nn   = lane & 15;      // A-row / B-col / D-col
    const int lg   = lane >> 4;      // lane group 0..3
    const int b0   = blockIdx.x * GRP;

    // H/X in B-fragment order: f16 index = (k>>5)*512 + (((k&31)>>3)*16+n)*8 + (k&7)
    __shared__ __align__(16) _Float16 Hf[2][2048];
    __shared__ __align__(16) _Float16 Xf[2][2048];
    __shared__ float red[8][GRP];

    const int mb = wave * 16;        // this wave's M-tile rows [mb, mb+16)

    // ---- A-fragments: 4+4 v8hf per wave (32 VGPRs of weights) ----
    v8hf wr0 = ld_afrag(W_r,  mb + nn,  0 + lg * 8);
    v8hf wr1 = ld_afrag(W_r,  mb + nn, 32 + lg * 8);
    v8hf wr2 = ld_afrag(W_r,  mb + nn, 64 + lg * 8);
    v8hf wr3 = ld_afrag(W_r,  mb + nn, 96 + lg * 8);
    v8hf wi0 = ld_afrag(W_in, mb + nn,  0 + lg * 8);
    v8hf wi1 = ld_afrag(W_in, mb + nn, 32 + lg * 8);
    v8hf wi2 = ld_afrag(W_in, mb + nn, 64 + lg * 8);
    v8hf wi3 = ld_afrag(W_in, mb + nn, 96 + lg * 8);

    // ---- per-lane D rows, bias, H write offset ----
    const int row0 = mb + 4 * lg;    // D rows row0..row0+3, col nn
    f32x4 bias;
#pragma unroll
    for (int r = 0; r < 4; ++r) bias[r] = b_in[row0 + r] + b_r[row0 + r];
    const int w0 = (row0 >> 5) * 512 + (((row0 & 31) >> 3) * 16 + nn) * 8 + (row0 & 7);

    // ---- X staging map (first 4 waves): thread loads 8 f32 of x[b0+xg][s][xseg*8..] ----
    const int xg = tid >> 4, xseg = tid & 15;          // valid for tid<256
    const float* xbase = (tid < 256)
        ? x + ((size_t)(b0 + xg) * S_LEN) * HDIM + xseg * 8 : x;
    const int xw = (xseg >> 2) * 512 + ((xseg & 3) * 16 + xg) * 8;

    // ---- prologue: zero H state, stage X[0] ----
    {
        const _Float16 z = (_Float16)0.0f;
        *reinterpret_cast<v4hf*>(&Hf[0][tid * 4]) = v4hf{z, z, z, z};
        if (tid < 256) {
            const float4* xp = reinterpret_cast<const float4*>(xbase);
            float4 a = xp[0], b = xp[1];
            *reinterpret_cast<v8hf*>(&Xf[0][xw]) =
                v8hf{(_Float16)a.x, (_Float16)a.y, (_Float16)a.z, (_Float16)a.w,
                     (_Float16)b.x, (_Float16)b.y, (_Float16)b.z, (_Float16)b.w};
        }
    }
    __syncthreads();

    f32x4 h = {0.f, 0.f, 0.f, 0.f};   // authoritative fp32 h (rows row0..+3, col nn)

#pragma unroll 1
    for (int s = 0; s < S_LEN; ++s) {
        // in-loop pins: keep the 8 weight frags loop-carried in VGPRs
        PIN(wr0); PIN(wr1); PIN(wr2); PIN(wr3);
        PIN(wi0); PIN(wi1); PIN(wi2); PIN(wi3);

        // prefetch next step's x into regs (vmcnt waited only at u==3 store)
        float4 pa = {0.f, 0.f, 0.f, 0.f}, pb = {0.f, 0.f, 0.f, 0.f};
        if (tid < 256 && s + 1 < S_LEN) {
            const float4* xp =
                reinterpret_cast<const float4*>(xbase + (size_t)(s + 1) * HDIM);
            pa = xp[0]; pb = xp[1];
        }

        // ---- phase 0: input map fused with unfold 0 ----
        f32x4 xin;
        {
            v8hf X0, X1, X2, X3, B0, B1, B2, B3;
            RDFRAGS(&Xf[s & 1][0], X0, X1, X2, X3);
            RDFRAGS(&Hf[0][0],     B0, B1, B2, B3);
            xin = MFMA(wi3, X3, MFMA(wi2, X2, MFMA(wi1, X1, MFMA(wi0, X0, bias))));
            f32x4 t = MFMA(wr3, B3, MFMA(wr2, B2, MFMA(wr1, B1, MFMA(wr0, B0, xin))));
            float v0 = fast_tanh(t[0]), v1 = fast_tanh(t[1]);
            float v2 = fast_tanh(t[2]), v3 = fast_tanh(t[3]);
            h[0] += DTC * (v0 - h[0]); h[1] += DTC * (v1 - h[1]);
            h[2] += DTC * (v2 - h[2]); h[3] += DTC * (v3 - h[3]);
            *reinterpret_cast<v4hf*>(&Hf[1][w0]) =
                v4hf{(_Float16)h[0], (_Float16)h[1], (_Float16)h[2], (_Float16)h[3]};
        }
        BAR();

        // ---- unfolds 1..5: single 4-deep MFMA chain, C = xin (no zero-init) ----
#pragma unroll
        for (int u = 1; u < NUNF; ++u) {
            v8hf B0, B1, B2, B3;
            RDFRAGS(&Hf[u & 1][0], B0, B1, B2, B3);
            f32x4 t = MFMA(wr3, B3, MFMA(wr2, B2, MFMA(wr1, B1, MFMA(wr0, B0, xin))));
            float v0 = fast_tanh(t[0]), v1 = fast_tanh(t[1]);
            float v2 = fast_tanh(t[2]), v3 = fast_tanh(t[3]);
            h[0] += DTC * (v0 - h[0]); h[1] += DTC * (v1 - h[1]);
            h[2] += DTC * (v2 - h[2]); h[3] += DTC * (v3 - h[3]);
            *reinterpret_cast<v4hf*>(&Hf[(u + 1) & 1][w0]) =
                v4hf{(_Float16)h[0], (_Float16)h[1], (_Float16)h[2], (_Float16)h[3]};
            if (u == 3 && tid < 256 && s + 1 < S_LEN) {   // vmcnt waited HERE
                *reinterpret_cast<v8hf*>(&Xf[(s + 1) & 1][xw]) =
                    v8hf{(_Float16)pa.x, (_Float16)pa.y, (_Float16)pa.z, (_Float16)pa.w,
                         (_Float16)pb.x, (_Float16)pb.y, (_Float16)pb.z, (_Float16)pb.w};
            }
            BAR();
        }
    }

    // ---- epilogue: out[b0+n] = sum_m h[m][n]*W_fc[m] + b_fc ----
    float p = h[0] * W_fc[row0] + h[1] * W_fc[row0 + 1]
            + h[2] * W_fc[row0 + 2] + h[3] * W_fc[row0 + 3];
    p += __shfl_xor(p, 16);
    p += __shfl_xor(p, 32);
    if (lane < 16) red[wave][lane] = p;
    __syncthreads();
    if (tid < GRP) {
        float acc = b_fc[0];
#pragma unroll
        for (int w = 0; w < 8; ++w) acc += red[w][tid];
        out[b0 + tid] = acc;
    }
}

extern "C" void kernel_launch(void* const* d_in, const int* in_sizes, int n_in,
                              void* d_out, int out_size, void* d_ws, size_t ws_size,
                              hipStream_t stream) {
    const float* x    = (const float*)d_in[0];
    const float* W_in = (const float*)d_in[1];
    const float* b_in = (const float*)d_in[2];
    const float* W_r  = (const float*)d_in[3];
    const float* b_r  = (const float*)d_in[4];
    const float* W_fc = (const float*)d_in[5];
    const float* b_fc = (const float*)d_in[6];
    float* outp = (float*)d_out;
    (void)in_sizes; (void)n_in; (void)out_size; (void)d_ws; (void)ws_size;
    ltc_kernel<<<dim3(512 / GRP), dim3(512), 0, stream>>>(x, W_in, b_in, W_r, b_r, W_fc, b_fc, outp);
}